// Round 1
// 1394.190 us; speedup vs baseline: 5.4947x; 5.4947x over previous
//
#include <hip/hip_runtime.h>
#include <cstdint>

// Problem: B=4, N=1024, C=768, H=12, hd=64
// Outputs fp32 concat: out[4,1024,768] then attn[4,12,1024,1024]
#define OUT0_ELEMS 3145728   // 4096*768
#define QKV_F32    3145728   // 48*1024*64 elements per tensor

// ---------------------------------------------------------------------------
// Tiled fp32 GEMM: C[M][O] = A[M][768] @ W[O][768]^T + bias
// BM=BN=128, BK=16, 256 threads, 8x8 micro-tile, XOR-swizzled LDS columns.
// SCATTER=1: qkv epilogue -> Q(*0.125)/K/V in [bh][n][d] layout.
// SCATTER=0: plain C0[m][o] write (proj).
// ---------------------------------------------------------------------------
template<int SCATTER>
__global__ __launch_bounds__(256)
void gemm128(const float* __restrict__ A, const float* __restrict__ W,
             const float* __restrict__ bias,
             float* __restrict__ C0, float* __restrict__ C1, float* __restrict__ C2)
{
    __shared__ float As[16][132];   // col-swizzled: col c stored at c ^ ((c&32)>>3)
    __shared__ float Ws[16][132];
    const int tid = threadIdx.x;
    const int tx = tid & 15;            // col group (8 cols)
    const int ty = tid >> 4;            // row group (8 rows)
    const int m0 = blockIdx.y * 128;
    const int o0 = blockIdx.x * 128;
    const int lr = tid >> 2;            // 0..63 (staging row)
    const int lk = (tid & 3) << 2;      // 0,4,8,12 (staging k)

    // swizzled store columns for rows lr and lr+64 (bit5 identical => +64)
    const int cs0 = lr ^ ((lr & 32) >> 3);
    const int cs1 = cs0 + 64;

    const float* Ar0 = A + (size_t)(m0 + lr) * 768 + lk;
    const float* Ar1 = Ar0 + (size_t)64 * 768;
    const float* Wr0 = W + (size_t)(o0 + lr) * 768 + lk;
    const float* Wr1 = Wr0 + (size_t)64 * 768;

    // swizzled read bases (each float4 group stays contiguous under the XOR)
    const int ab = ty << 3;
    const int ax = (ab & 32) >> 3;
    const int a0i = ab ^ ax, a1i = (ab + 4) ^ ax;
    const int bb = tx << 3;
    const int bx = (bb & 32) >> 3;
    const int b0i = bb ^ bx, b1i = (bb + 4) ^ bx;

    float acc[8][8] = {};

    for (int k0 = 0; k0 < 768; k0 += 16) {
        float4 av0 = *(const float4*)(Ar0 + k0);
        float4 av1 = *(const float4*)(Ar1 + k0);
        float4 wv0 = *(const float4*)(Wr0 + k0);
        float4 wv1 = *(const float4*)(Wr1 + k0);
        __syncthreads();   // previous tile's reads complete
        As[lk+0][cs0]=av0.x; As[lk+1][cs0]=av0.y; As[lk+2][cs0]=av0.z; As[lk+3][cs0]=av0.w;
        As[lk+0][cs1]=av1.x; As[lk+1][cs1]=av1.y; As[lk+2][cs1]=av1.z; As[lk+3][cs1]=av1.w;
        Ws[lk+0][cs0]=wv0.x; Ws[lk+1][cs0]=wv0.y; Ws[lk+2][cs0]=wv0.z; Ws[lk+3][cs0]=wv0.w;
        Ws[lk+0][cs1]=wv1.x; Ws[lk+1][cs1]=wv1.y; Ws[lk+2][cs1]=wv1.z; Ws[lk+3][cs1]=wv1.w;
        __syncthreads();   // stores visible
        #pragma unroll
        for (int kk = 0; kk < 16; ++kk) {
            float4 aL = *(const float4*)&As[kk][a0i];
            float4 aH = *(const float4*)&As[kk][a1i];
            float4 bL = *(const float4*)&Ws[kk][b0i];
            float4 bH = *(const float4*)&Ws[kk][b1i];
            float a[8] = {aL.x,aL.y,aL.z,aL.w,aH.x,aH.y,aH.z,aH.w};
            float b[8] = {bL.x,bL.y,bL.z,bL.w,bH.x,bH.y,bH.z,bH.w};
            #pragma unroll
            for (int i = 0; i < 8; ++i)
                #pragma unroll
                for (int j = 0; j < 8; ++j)
                    acc[i][j] = fmaf(a[i], b[j], acc[i][j]);
        }
    }

    const float4 bj0 = *(const float4*)(bias + o0 + bb);
    const float4 bj1 = *(const float4*)(bias + o0 + bb + 4);

    if (SCATTER) {
        // columns o0+bb..o0+bb+7 are within one (tensor, head): 768%128==0, 8|64
        const int oc   = o0 + bb;
        const int sidx = oc / 768;
        const int rem  = oc - sidx * 768;
        const int h = rem >> 6, d0 = rem & 63;
        const float scale = (sidx == 0) ? 0.125f : 1.0f;
        float* T = (sidx == 0) ? C0 : ((sidx == 1) ? C1 : C2);
        const int b = m0 >> 10;           // 128 | 1024 => constant in tile
        float* Tb = T + ((size_t)(b * 12 + h) * 1024) * 64 + d0;
        #pragma unroll
        for (int i = 0; i < 8; ++i) {
            const int n = (m0 & 1023) + (ty << 3) + i;
            float4 r0, r1;
            r0.x=(acc[i][0]+bj0.x)*scale; r0.y=(acc[i][1]+bj0.y)*scale;
            r0.z=(acc[i][2]+bj0.z)*scale; r0.w=(acc[i][3]+bj0.w)*scale;
            r1.x=(acc[i][4]+bj1.x)*scale; r1.y=(acc[i][5]+bj1.y)*scale;
            r1.z=(acc[i][6]+bj1.z)*scale; r1.w=(acc[i][7]+bj1.w)*scale;
            *(float4*)(Tb + (size_t)n * 64)     = r0;
            *(float4*)(Tb + (size_t)n * 64 + 4) = r1;
        }
    } else {
        #pragma unroll
        for (int i = 0; i < 8; ++i) {
            const int m = m0 + (ty << 3) + i;
            float4 r0, r1;
            r0.x=acc[i][0]+bj0.x; r0.y=acc[i][1]+bj0.y;
            r0.z=acc[i][2]+bj0.z; r0.w=acc[i][3]+bj0.w;
            r1.x=acc[i][4]+bj1.x; r1.y=acc[i][5]+bj1.y;
            r1.z=acc[i][6]+bj1.z; r1.w=acc[i][7]+bj1.w;
            *(float4*)(C0 + (size_t)m * 768 + o0 + bb)     = r0;
            *(float4*)(C0 + (size_t)m * 768 + o0 + bb + 4) = r1;
        }
    }
}

// ---------------------------------------------------------------------------
// Fused attention: 16 query rows per block. scores (Q broadcast from LDS,
// K row in registers) -> wave-parallel softmax (16 lanes/row) -> row0 fix ->
// attn write (float4 coalesced) -> O1 = P @ V from LDS.
// grid = (64 row-tiles, 48 bh), 256 threads, 68 KB LDS (2 blocks/CU).
// ---------------------------------------------------------------------------
__global__ __launch_bounds__(256)
void attn_fused(const float* __restrict__ Q, const float* __restrict__ K,
                const float* __restrict__ V, const float* __restrict__ cls_bias,
                float* __restrict__ attn, float* __restrict__ O1)
{
    __shared__ float s[16 * 1024];   // 64 KB: 16 score rows
    __shared__ float qs[16 * 64];    // 4 KB: Q tile (already scaled by 0.125)
    const int tid = threadIdx.x;
    const int bh  = blockIdx.y;
    const int rt  = blockIdx.x;
    const int q0  = rt << 4;
    const size_t bhoff = (size_t)bh << 16;   // bh * 1024 * 64

    ((float4*)qs)[tid] = ((const float4*)(Q + bhoff + ((size_t)q0 << 6)))[tid];
    __syncthreads();

    // ---- phase 1: S[q][key] = Q[q] . K[key], key = chunk*256 + tid ----
    const float* Kb = K + bhoff;
    #pragma unroll 1
    for (int chunk = 0; chunk < 4; ++chunk) {
        const int key = (chunk << 8) + tid;
        float4 kreg[16];
        const float4* Kr = (const float4*)(Kb + ((size_t)key << 6));
        #pragma unroll
        for (int j = 0; j < 16; ++j) kreg[j] = Kr[j];
        #pragma unroll
        for (int q = 0; q < 16; ++q) {
            const float4* Qr = (const float4*)(qs + (q << 6));
            float a0 = 0.f, a1 = 0.f, a2 = 0.f, a3 = 0.f;
            #pragma unroll
            for (int j = 0; j < 16; ++j) {
                float4 qv = Qr[j];            // broadcast ds_read_b128
                a0 = fmaf(qv.x, kreg[j].x, a0);
                a1 = fmaf(qv.y, kreg[j].y, a1);
                a2 = fmaf(qv.z, kreg[j].z, a2);
                a3 = fmaf(qv.w, kreg[j].w, a3);
            }
            s[(q << 10) + key] = (a0 + a1) + (a2 + a3);
        }
    }
    __syncthreads();

    // ---- phase 2: softmax, 16 lanes per row; (j+q) rotation keeps banks 2-way
    {
        const int q = tid >> 4, sub = tid & 15;
        float* row = s + (q << 10);
        float mx = -3.0e38f;
        #pragma unroll 4
        for (int j = 0; j < 64; ++j)
            mx = fmaxf(mx, row[sub + (((j + q) & 63) << 4)]);
        #pragma unroll
        for (int off = 8; off; off >>= 1) mx = fmaxf(mx, __shfl_xor(mx, off, 16));
        float sm = 0.f;
        #pragma unroll 4
        for (int j = 0; j < 64; ++j) {
            const int k = sub + (((j + q) & 63) << 4);
            const float e = __expf(row[k] - mx);
            row[k] = e;
            sm += e;
        }
        #pragma unroll
        for (int off = 8; off; off >>= 1) sm += __shfl_xor(sm, off, 16);
        const float inv = 1.0f / sm;
        #pragma unroll 4
        for (int j = 0; j < 64; ++j)
            row[sub + (((j + q) & 63) << 4)] *= inv;
    }

    // ---- row0 fix: global query 0 of this (b,h); lanes 0..15 (one wave) ----
    if (rt == 0 && tid < 16) {
        const float p0  = s[0];
        const float a00 = fminf(fmaxf(p0 + cls_bias[bh % 12], 0.f), 1.f);
        float actual = 0.f;
        for (int j = 0; j < 64; ++j) {
            const int k = tid + (j << 4);
            if (k) actual += s[k];
        }
        #pragma unroll
        for (int off = 8; off; off >>= 1) actual += __shfl_xor(actual, off, 16);
        const float mp = (1.0f - a00) / (actual + 1e-6f);
        for (int j = 0; j < 64; ++j) {
            const int k = tid + (j << 4);
            s[k] = (k == 0) ? a00 : fminf(fmaxf(s[k] * mp, 0.f), 1.f);
        }
    }
    __syncthreads();

    // ---- phase 3: write attn (output 1), coalesced float4 ----
    {
        float4* dst = (float4*)(attn + ((size_t)bh << 20) + ((size_t)q0 << 10));
        const float4* src = (const float4*)s;
        #pragma unroll
        for (int i = 0; i < 16; ++i)
            dst[tid + (i << 8)] = src[tid + (i << 8)];
    }

    // ---- phase 4: O1[q][d0..d0+3] = sum_k P[q][k] * V[k][d] ----
    {
        const int q = tid >> 4, d0 = (tid & 15) << 2;
        const float* Vb  = V + bhoff + d0;
        const float* row = s + (q << 10);
        float4 accA = {0,0,0,0}, accB = {0,0,0,0};   // 2 chains: latency cover
        for (int k = 0; k < 1024; k += 4) {
            float4 p  = *(const float4*)(row + k);   // broadcast within 16 lanes
            float4 v0 = *(const float4*)(Vb + ((size_t)(k+0) << 6));
            float4 v1 = *(const float4*)(Vb + ((size_t)(k+1) << 6));
            float4 v2 = *(const float4*)(Vb + ((size_t)(k+2) << 6));
            float4 v3 = *(const float4*)(Vb + ((size_t)(k+3) << 6));
            accA.x = fmaf(p.x, v0.x, accA.x); accA.y = fmaf(p.x, v0.y, accA.y);
            accA.z = fmaf(p.x, v0.z, accA.z); accA.w = fmaf(p.x, v0.w, accA.w);
            accA.x = fmaf(p.y, v1.x, accA.x); accA.y = fmaf(p.y, v1.y, accA.y);
            accA.z = fmaf(p.y, v1.z, accA.z); accA.w = fmaf(p.y, v1.w, accA.w);
            accB.x = fmaf(p.z, v2.x, accB.x); accB.y = fmaf(p.z, v2.y, accB.y);
            accB.z = fmaf(p.z, v2.z, accB.z); accB.w = fmaf(p.z, v2.w, accB.w);
            accB.x = fmaf(p.w, v3.x, accB.x); accB.y = fmaf(p.w, v3.y, accB.y);
            accB.z = fmaf(p.w, v3.z, accB.z); accB.w = fmaf(p.w, v3.w, accB.w);
        }
        float4 r;
        r.x = accA.x + accB.x; r.y = accA.y + accB.y;
        r.z = accA.z + accB.z; r.w = accA.w + accB.w;
        const int b = bh / 12, h = bh - b * 12;
        const int n = q0 + q;
        *(float4*)(O1 + ((size_t)(b * 1024 + n)) * 768 + (h << 6) + d0) = r;
    }
}

extern "C" void kernel_launch(void* const* d_in, const int* in_sizes, int n_in,
                              void* d_out, int out_size, void* d_ws, size_t ws_size,
                              hipStream_t stream) {
    const float* x        = (const float*)d_in[0];
    const float* qkv_w    = (const float*)d_in[1];
    const float* qkv_b    = (const float*)d_in[2];
    const float* proj_w   = (const float*)d_in[3];
    const float* proj_b   = (const float*)d_in[4];
    const float* cls_bias = (const float*)d_in[5];

    float* out  = (float*)d_out;
    float* attn = out + OUT0_ELEMS;

    float* ws = (float*)d_ws;
    float* Q  = ws;                       // 12.6 MB (pre-scaled by 0.125)
    float* K  = Q  + (size_t)QKV_F32;     // 12.6 MB
    float* V  = K  + (size_t)QKV_F32;     // 12.6 MB
    float* O1 = V  + (size_t)QKV_F32;     // 12.6 MB

    // 1) qkv = x @ qkv_w.T + qkv_b -> Q(scaled)/K/V   (tiled, compute-bound)
    gemm128<1><<<dim3(18, 32), 256, 0, stream>>>(x, qkv_w, qkv_b, Q, K, V);
    // 2+3) fused scores/softmax/row0fix -> attn (output 1) and O1 = attn @ V
    attn_fused<<<dim3(64, 48), 256, 0, stream>>>(Q, K, V, cls_bias, attn, O1);
    // 4) out = O1 @ proj_w.T + proj_b (output 0)
    gemm128<0><<<dim3(6, 32), 256, 0, stream>>>(O1, proj_w, proj_b, out, nullptr, nullptr);
}